// Round 3
// baseline (123.215 us; speedup 1.0000x reference)
//
#include <hip/hip_runtime.h>

#define B_ 32
#define N_ 1024
#define F_ 128
#define D_ 128
// dk = 128^-0.5 / 1024
#define DK_CONST 8.631674575031098e-05f
#define NM1 1023.0f

typedef unsigned short u16;
typedef __attribute__((ext_vector_type(8))) short short8;
typedef __attribute__((ext_vector_type(4))) float floatx4;

__device__ __forceinline__ u16 f2b(float x) {
    union { float f; unsigned u; } v; v.f = x;
    unsigned u = v.u;
    return (u16)((u + 0x7FFFu + ((u >> 16) & 1u)) >> 16);
}
__device__ __forceinline__ float b2f(u16 h) {
    union { unsigned u; float f; } v; v.u = ((unsigned)h) << 16;
    return v.f;
}

// ============ K1: blocks 0..255 colsum partials; 256..319 Mt rows; 320 bias vectors ============
// wcv layout: [0..127]=wc, [128..255]=w2, [256]=bq.bk
__global__ __launch_bounds__(256) void k1_prep(const float* __restrict__ aq,
                                               const float* __restrict__ Wq,
                                               const float* __restrict__ Wk,
                                               const float* __restrict__ bq,
                                               const float* __restrict__ bk,
                                               float* __restrict__ colsumPart,
                                               u16* __restrict__ Mt,
                                               float* __restrict__ wcv,
                                               int* __restrict__ counterB) {
    __shared__ float wq[128][129];
    __shared__ float vsm[2][128];
    __shared__ float red[256];
    __shared__ float cspart[256][4];
    int t = threadIdx.x;
    int blk = blockIdx.x;
    if (blk < 256) {
        if (blk == 0 && t < 32) counterB[t] = 0;
        const float4* aq4 = (const float4*)(aq + (size_t)blk * 128 * 128);
        float c0 = 0.f, c1 = 0.f, c2 = 0.f, c3 = 0.f;
        for (int j = 0; j < 16; ++j) {
            float4 v = aq4[t + 256 * j];
            c0 += v.x; c1 += v.y; c2 += v.z; c3 += v.w;
        }
        cspart[t][0] = c0; cspart[t][1] = c1; cspart[t][2] = c2; cspart[t][3] = c3;
        __syncthreads();
        if (t < 128) {
            int c4i = t >> 2, comp = t & 3;
            float s = 0.f;
            for (int h = 0; h < 8; ++h) s += cspart[h * 32 + c4i][comp];
            colsumPart[blk * 128 + t] = s;
        }
    } else if (blk < 320) {
        int mb = blk - 256;                 // rows 2mb, 2mb+1 of Mt
        int h = t >> 7, f = t & 127;
        for (int j = 0; j < 64; ++j) {
            int idx = t + 256 * j;
            wq[idx >> 7][idx & 127] = Wq[idx];
        }
        vsm[h][f] = Wk[(mb * 2 + h) * 128 + f];
        __syncthreads();
        float s = 0.f;
        for (int d = 0; d < 128; ++d) s += vsm[h][d] * wq[f][d];
        Mt[(mb * 2 + h) * 128 + f] = f2b(s);
    } else {
        // bias-vector block
        if (t < 128) { vsm[0][t] = bq[t]; vsm[1][t] = bk[t]; }
        red[t] = (t < 128) ? (fabsf(bq[t]) + fabsf(bk[t])) : 0.f;
        __syncthreads();
        for (int st = 128; st > 0; st >>= 1) { if (t < st) red[t] += red[t + st]; __syncthreads(); }
        float nb = red[0];
        __syncthreads();
        if (nb != 0.f) {                    // block-uniform branch
            for (int j = 0; j < 64; ++j) {
                int idx = t + 256 * j;
                wq[idx >> 7][idx & 127] = Wq[idx];
            }
            __syncthreads();
            float w1 = 0.f;
            if (t < 128) for (int d = 0; d < 128; ++d) w1 += wq[t][d] * vsm[1][d];
            __syncthreads();
            for (int j = 0; j < 64; ++j) {
                int idx = t + 256 * j;
                wq[idx >> 7][idx & 127] = Wk[idx];
            }
            red[t] = (t < 128) ? vsm[0][t] * vsm[1][t] : 0.f;
            __syncthreads();
            float w2v = 0.f;
            if (t < 128) for (int d = 0; d < 128; ++d) w2v += wq[t][d] * vsm[0][d];
            for (int st = 128; st > 0; st >>= 1) { if (t < st) red[t] += red[t + st]; __syncthreads(); }
            if (t < 128) { wcv[t] = NM1 * w1 - w2v; wcv[128 + t] = w2v; }
            if (t == 0) wcv[256] = red[0];
        } else {
            if (t < 128) { wcv[t] = 0.f; wcv[128 + t] = 0.f; }
            if (t == 0) wcv[256] = 0.f;
        }
    }
}

// ============ K2: MFMA U=Aq*M; agg = mask*dk*(U.(S-aq) + aq.wc + Cb); ssq partials ============
__global__ __launch_bounds__(256) void k2_agg(const float* __restrict__ aq,
                                              const u16* __restrict__ Mt,
                                              const float* __restrict__ mask,
                                              const float* __restrict__ colsumPart,
                                              const float* __restrict__ wcv,
                                              float* __restrict__ agg,
                                              float* __restrict__ ssqPart) {
    __shared__ __align__(16) u16 aqT[128][136];
    __shared__ __align__(16) u16 mtT[128][136];
    __shared__ float qpart[2][128];
    __shared__ float Sl[128], wcl[128];
    __shared__ float red[256];

    int t = threadIdx.x;
    int tile = blockIdx.x;
    int b = tile >> 3;
    const float* aqBlk = aq + (size_t)tile * 128 * 128;

    for (int j = 0; j < 16; ++j) {
        int idx = t + 256 * j;
        int row = idx >> 5;
        int c4  = idx & 31;
        float4 v = ((const float4*)aqBlk)[idx];
        ushort4 bb;
        bb.x = f2b(v.x); bb.y = f2b(v.y); bb.z = f2b(v.z); bb.w = f2b(v.w);
        *((ushort4*)&aqT[row][c4 * 4]) = bb;
    }
    for (int j = 0; j < 16; ++j) {
        int idx = t + 256 * j;
        int row = idx >> 5;
        int c4  = idx & 31;
        ushort4 mv = ((const ushort4*)Mt)[idx];
        *((ushort4*)&mtT[row][c4 * 4]) = mv;
    }
    float s = 0.f;
    if (t < 128) {
        for (int h = 0; h < 8; ++h) s += colsumPart[(b * 8 + h) * 128 + t];
        Sl[t] = s;
        wcl[t] = wcv[t];
    }
    red[t] = (t < 128) ? s * wcv[128 + t] : 0.f;
    __syncthreads();
    for (int st = 128; st > 0; st >>= 1) { if (t < st) red[t] += red[t + st]; __syncthreads(); }
    float Cbv = red[0] + NM1 * wcv[256];

    int w = t >> 6;
    int lane = t & 63;
    int wr   = (w >> 1) * 64;
    int wcol = (w & 1) * 64;
    int lm = lane & 15;
    int lq = lane >> 4;

    floatx4 acc[4][4];
    for (int i = 0; i < 4; ++i)
        for (int j = 0; j < 4; ++j)
            acc[i][j] = (floatx4){0.f, 0.f, 0.f, 0.f};

    for (int ks = 0; ks < 4; ++ks) {
        int k0 = ks * 32 + lq * 8;
        short8 afr[4], bfr[4];
        for (int i = 0; i < 4; ++i) {
            afr[i] = *(const short8*)&aqT[wr + i * 16 + lm][k0];
            bfr[i] = *(const short8*)&mtT[wcol + i * 16 + lm][k0];
        }
        for (int i = 0; i < 4; ++i)
            for (int j = 0; j < 4; ++j)
                acc[i][j] = __builtin_amdgcn_mfma_f32_16x16x32_bf16(afr[i], bfr[j], acc[i][j], 0, 0, 0);
    }

    for (int mi = 0; mi < 4; ++mi) {
        for (int r = 0; r < 4; ++r) {
            int row = wr + mi * 16 + lq * 4 + r;
            float sx = 0.f;
            for (int nj = 0; nj < 4; ++nj) {
                int col = wcol + nj * 16 + lm;
                float av = b2f(aqT[row][col]);
                float T  = acc[mi][nj][r];
                sx += T * (Sl[col] - av) + av * wcl[col];
            }
            for (int d = 1; d < 16; d <<= 1) sx += __shfl_xor(sx, d);
            if (lm == 0) qpart[w & 1][row] = sx;
        }
    }
    __syncthreads();
    float a2 = 0.f;
    if (t < 128) {
        int atom = tile * 128 + t;
        float a = mask[atom] * DK_CONST * (qpart[0][t] + qpart[1][t] + Cbv);
        agg[atom] = a;
        a2 = a * a;
    }
    red[t] = a2;
    __syncthreads();
    for (int st = 128; st > 0; st >>= 1) { if (t < st) red[t] += red[t + st]; __syncthreads(); }
    if (t == 0) ssqPart[tile] = red[0];
}

// ============ K3: e=mask*exp(agg*invn); partials; last block per batch finalizes ============
__global__ __launch_bounds__(256) void k3_fin(const float* __restrict__ aq,
                                              const float* __restrict__ mask,
                                              const float* __restrict__ Wv,
                                              const float* __restrict__ bv,
                                              const float* __restrict__ agg,
                                              const float* __restrict__ ssqPart,
                                              float* __restrict__ Epart,
                                              float* __restrict__ ctxPart,
                                              int* __restrict__ counterB,
                                              float* __restrict__ attnOut,
                                              float* __restrict__ ctxOut) {
    __shared__ float el[128];
    __shared__ float red[256];
    __shared__ float cp[2][128];
    __shared__ float shInvn;
    __shared__ int shOld;
    int b = blockIdx.x, s = blockIdx.y, t = threadIdx.x;
    int base = b * N_ + s * 128;

    if (t == 0) {
        float ss = 0.f;
        for (int h = 0; h < 8; ++h) ss += ssqPart[b * 8 + h];
        shInvn = 1.0f / sqrtf(ss);
    }
    __syncthreads();
    float invn = shInvn;
    float e = 0.f;
    if (t < 128) {
        float a = agg[base + t];
        float m = mask[base + t];
        e = (m > 0.5f) ? expf(a * invn) : 0.f;   // agg*invn <= 1, no max needed
        el[t] = e;
        attnOut[base + t] = e;                    // unnormalized; last block rescales
    }
    red[t] = e;
    __syncthreads();
    for (int st = 128; st > 0; st >>= 1) { if (t < st) red[t] += red[t + st]; __syncthreads(); }
    if (t == 0) Epart[b * 8 + s] = red[0];

    int f = t & 127, hh = t >> 7;
    const float* aqs = aq + (size_t)base * 128;
    float acc = 0.f;
    for (int r = hh; r < 128; r += 2) acc += el[r] * aqs[r * 128 + f];
    cp[hh][f] = acc;
    __syncthreads();
    if (t < 128) ctxPart[(b * 8 + s) * 128 + t] = cp[0][t] + cp[1][t];

    __threadfence();
    __syncthreads();
    if (t == 0) shOld = atomicAdd(&counterB[b], 1);
    __syncthreads();
    if (shOld == 7) {
        __threadfence();
        float E = 0.f;
        for (int h = 0; h < 8; ++h) E += Epart[b * 8 + h];
        float invE = 1.0f / E;
        if (t < 128) {
            float p = 0.f;
            for (int h = 0; h < 8; ++h) p += ctxPart[(b * 8 + h) * 128 + t];
            el[t] = p;
        }
        __syncthreads();
        int th = t & 127, half = t >> 7;
        float c = 0.f;
        for (int ff = half * 64; ff < half * 64 + 64; ++ff) c += el[ff] * Wv[ff * 128 + th];
        cp[half][th] = c;
        __syncthreads();
        if (t < 128)
            ctxOut[b * 128 + t] = (cp[0][t] + cp[1][t]) * invE + bv[t];
        for (int j = 0; j < 4; ++j) {
            int i = b * N_ + j * 256 + t;
            attnOut[i] *= invE;
        }
    }
}

extern "C" void kernel_launch(void* const* d_in, const int* in_sizes, int n_in,
                              void* d_out, int out_size, void* d_ws, size_t ws_size,
                              hipStream_t stream) {
    const float* aq   = (const float*)d_in[0];   // [B,N,F]
    const float* mask = (const float*)d_in[1];   // [B,N,1]
    const float* Wq   = (const float*)d_in[2];
    const float* bq   = (const float*)d_in[3];
    const float* Wk   = (const float*)d_in[4];
    const float* bk   = (const float*)d_in[5];
    const float* Wv   = (const float*)d_in[6];
    const float* bv   = (const float*)d_in[7];

    float* out_attn = (float*)d_out;             // [B,N,1] = 32768
    float* out_ctx  = out_attn + B_ * N_;        // [B,D]   = 4096

    float* wsf        = (float*)d_ws;
    float* colsumPart = wsf;                     // 32768
    float* agg        = wsf + 32768;             // 32768
    float* ssqPart    = wsf + 65536;             // 256
    float* wcv        = wsf + 65792;             // 288 (257 used)
    float* Epart      = wsf + 66080;             // 256
    float* ctxPart    = wsf + 66336;             // 32768
    int*   counterB   = (int*)(wsf + 99104);     // 32
    u16*   Mt         = (u16*)(wsf + 99136);     // 128x128 bf16 = 4096 floats

    k1_prep<<<321, 256, 0, stream>>>(aq, Wq, Wk, bq, bk, colsumPart, Mt, wcv, counterB);
    k2_agg<<<256, 256, 0, stream>>>(aq, Mt, mask, colsumPart, wcv, agg, ssqPart);
    k3_fin<<<dim3(32, 8), 256, 0, stream>>>(aq, mask, Wv, bv, agg, ssqPart,
                                            Epart, ctxPart, counterB, out_attn, out_ctx);
}